// Round 15
// baseline (211.970 us; speedup 1.0000x reference)
//
#include <hip/hip_runtime.h>
#include <hip/hip_bf16.h>

#define HW 65536
#define NCH 32   // channel chunks in k_dw (1 oct each)

typedef __attribute__((ext_vector_type(8))) short bf16x8;
typedef __attribute__((ext_vector_type(4))) float f32x4;
typedef __attribute__((ext_vector_type(2))) float f32x2;
typedef __attribute__((ext_vector_type(2))) short s16x2;

__device__ __forceinline__ float bfu(unsigned short u){
    return __uint_as_float(((unsigned int)u) << 16);
}
__device__ __forceinline__ float bflo(unsigned int u){
    return __uint_as_float(u << 16);
}
__device__ __forceinline__ float bfhi(unsigned int u){
    return __uint_as_float(u & 0xffff0000u);
}
__device__ __forceinline__ unsigned short f2bu(float f){
    return __builtin_bit_cast(unsigned short, __float2bfloat16(f));
}
__device__ __forceinline__ unsigned int pk2(float a, float b){
    return (unsigned int)f2bu(a) | ((unsigned int)f2bu(b) << 16);
}
// v_cvt_pk_bf16_f32: packs (a,b) -> (lo=bf16(a), hi=bf16(b)), RTNE. No builtin on gfx950.
__device__ __forceinline__ unsigned int pk2c(float a, float b){
    unsigned int r;
    asm("v_cvt_pk_bf16_f32 %0, %1, %2" : "=v"(r) : "v"(a), "v"(b));
    return r;
}

#if __has_builtin(__builtin_amdgcn_fdot2_f32_bf16)
__device__ __forceinline__ float DOT2B(s16x2 a, s16x2 b, float c){
    return __builtin_amdgcn_fdot2_f32_bf16(a, b, c, false);
}
#else
__device__ __forceinline__ float DOT2B(s16x2 a, s16x2 b, float c){
    return fmaf(bfu((unsigned short)a.x), bfu((unsigned short)b.x),
           fmaf(bfu((unsigned short)a.y), bfu((unsigned short)b.y), c));
}
#endif

// ---------------- K0a: sequential coefficient core (1 block) ----------------
__global__ void k_coef1(const float* __restrict__ wlp1, const float* __restrict__ whp1,
                        const float* __restrict__ wlp2,
                        float* __restrict__ ahp1s,
                        float* __restrict__ cpG, float* __restrict__ cnG){
    __shared__ float aL[508], ah[508];
    int t = threadIdx.x;
    if (t < 508){
        int g = t >> 2, o = t & 3;
        float s = 0.f, s2 = 0.f;
        for (int i = 0; i < 4; ++i){ s += wlp1[g*16 + o*4 + i]; s2 += whp1[g*16 + o*4 + i]; }
        aL[t] = s; ah[t] = s2;
    }
    __syncthreads();
    if (t < 508){
        int g = t >> 2, o = t & 3;
        float p = 0.f, n = 0.f;
        for (int k = 0; k < 4; ++k){
            int idx = 4*g + k;                    // shuffled position
            int inv = (idx % 127)*4 + idx/127;    // original channel
            float av = aL[inv];
            float w2 = wlp2[g*16 + o*4 + k];
            p += w2 * fmaxf(av, 0.f);
            n += w2 * fminf(av, 0.f);
        }
        cpG[t] = p; cnG[t] = n;
        int inv = (t % 127)*4 + t/127;
        ahp1s[t] = ah[inv];
    }
}

// ---------------- K0b: parallel table fills (64 blocks, grid-strided) ----------------
__global__ void k_coef2(const float* __restrict__ wld, const float* __restrict__ whd,
                        const float* __restrict__ winP, const float* __restrict__ winD,
                        const float* __restrict__ wout,
                        const float* __restrict__ cp, const float* __restrict__ cn,
                        unsigned int* __restrict__ WPNL, unsigned int* __restrict__ WPNH,
                        unsigned int* __restrict__ WLDpk, unsigned int* __restrict__ WHDpk,
                        float* __restrict__ wDp,
                        unsigned short* __restrict__ WPb, unsigned short* __restrict__ BtP){
    int t0 = blockIdx.x*256 + threadIdx.x;
    int str = gridDim.x*256;
    // analytic tables, packed (pos,neg) bf16 pairs
    for (int idx = t0; idx < 127*9; idx += str){
        int g = idx/9, q = idx%9;
        float lp=0.f, ln=0.f, hp=0.f, hn=0.f;
        for (int i = 0; i < 4; ++i){
            int ch = 4*g + i;
            if (ch < 254){ float w = wld[g*36 + i*9 + q]; lp += w*cp[ch]; ln += w*cn[ch]; }
            else         { float w = whd[g*36 + i*9 + q]; hp += w*cp[ch]; hn += w*cn[ch]; }
        }
        WPNL[idx] = pk2(lp, ln);
        WPNH[idx] = pk2(hp, hn);
    }
    // conv tables, packed channel-pair bf16 weights (masked to h2-sourced channels)
    for (int idx = t0; idx < 127*18; idx += str){
        int g = idx/18, r = idx%18; int q = r >> 1, hp_ = r & 1;
        int c0 = 4*g + 2*hp_, c1 = c0 + 1;
        float wl0 = (c0 >= 254) ? wld[g*36 + (2*hp_)*9 + q]   : 0.f;
        float wl1 = (c1 >= 254) ? wld[g*36 + (2*hp_+1)*9 + q] : 0.f;
        float wh0 = (c0 <  254) ? whd[g*36 + (2*hp_)*9 + q]   : 0.f;
        float wh1 = (c1 <  254) ? whd[g*36 + (2*hp_+1)*9 + q] : 0.f;
        WLDpk[idx] = pk2(wl0, wl1);
        WHDpk[idx] = pk2(wh0, wh1);
    }
    // wDp: [512 tch][9], zero-padded winD (508x9)
    for (int idx = t0; idx < 512*9; idx += str){
        int ch = idx/9, q = idx - ch*9;
        wDp[idx] = (ch < 508) ? winD[ch*9 + q] : 0.f;
    }
    // WPb: [256 o][64 k] bf16, zero-padded winP
    for (int idx = t0; idx < 256*64; idx += str){
        int o = idx >> 6, k = idx & 63;
        float vv = (o < 254 && k < 48) ? winP[o*48 + k] : 0.f;
        WPb[idx] = f2bu(vv);
    }
    // BtP: [48 n][256 k] bf16; k=2g -> wout[n][g] (l), k=2g+1 -> wout[n][127+g] (h)
    for (int idx = t0; idx < 48*256; idx += str){
        int n = idx >> 8, k = idx & 255;
        int g = k >> 1;
        float vv = (g < 127) ? ((k & 1) ? wout[n*254 + 127 + g] : wout[n*254 + g]) : 0.f;
        BtP[idx] = f2bu(vv);
    }
}

// ---------------- per-band border zeroing ----------------
__global__ void k_padU(uint4* __restrict__ u, float* __restrict__ Lm, unsigned int* __restrict__ Lpk,
                       int uRp, int lRp, int nbat, int zeroTop, int zeroBot){
    int p = blockIdx.x, t = threadIdx.x;
    int nu = nbat*32;
    if (p < nu){
        uint4* pl = u + (size_t)p*uRp*258;
        uint4 z = make_uint4(0,0,0,0);
        for (int i = t; i < 258; i += 256){ pl[i] = z; pl[(size_t)(uRp-1)*258 + i] = z; }
        for (int r = t; r < uRp; r += 256){ pl[(size_t)r*258] = z; pl[(size_t)r*258 + 257] = z; }
    } else {
        float* pl = Lm + (size_t)(p-nu)*lRp*258;
        unsigned int* pk = Lpk + (size_t)(p-nu)*lRp*258;
        if (zeroTop) for (int i = t; i < 258; i += 256){ pl[i] = 0.f; pk[i] = 0u; }
        if (zeroBot) for (int i = t; i < 258; i += 256){ pl[(size_t)(lRp-1)*258 + i] = 0.f; pk[(size_t)(lRp-1)*258 + i] = 0u; }
        for (int r = t; r < lRp; r += 256){
            pl[(size_t)r*258] = 0.f; pl[(size_t)r*258 + 257] = 0.f;
            pk[(size_t)r*258] = 0u;  pk[(size_t)r*258 + 257] = 0u;
        }
    }
}

// ---------------- K1a: u = w_inP @ x (1x1 48->254) via MFMA, padded oct layout ----------------
__global__ __launch_bounds__(256) void k_pconv(const float* __restrict__ x,
        const unsigned short* __restrict__ WPb, uint4* __restrict__ u,
        int b0, int ur0, int urows, int uRp){
    __shared__ unsigned short BtS[256*72];   // 36864 B; epilogue overlays [64px][264 u16]=33792 B
    int t = threadIdx.x;
    for (int i = t; i < 256*64; i += 256){
        int o = i >> 6, k = i & 63;
        BtS[o*72 + k] = WPb[i];
    }
    int bpb = urows*4;
    int bi = blockIdx.x / bpb;
    int r  = blockIdx.x - bi*bpb;
    int lr = r >> 2, quarter = r & 3;
    int b = b0 + bi;
    int grow = ur0 + lr;
    const float* xb = x + (size_t)b*48*HW + (size_t)grow*256 + quarter*64;
    int w = t >> 6, lane = t & 63;
    int px = w*16 + (lane & 15);
    int k0 = (lane >> 4)*8;
    bf16x8 afr[2];
    #pragma unroll
    for (int kk = 0; kk < 2; ++kk){
        #pragma unroll
        for (int j = 0; j < 8; ++j){
            int k = kk*32 + k0 + j;
            float vv = (k < 48) ? xb[(size_t)k*HW + px] : 0.f;
            afr[kk][j] = (short)f2bu(vv);
        }
    }
    __syncthreads();
    f32x4 acc[16];
    #pragma unroll
    for (int nt = 0; nt < 16; ++nt) acc[nt] = (f32x4){0.f,0.f,0.f,0.f};
    #pragma unroll
    for (int kk = 0; kk < 2; ++kk){
        #pragma unroll
        for (int nt = 0; nt < 16; ++nt){
            bf16x8 bfr = *reinterpret_cast<const bf16x8*>(&BtS[(nt*16 + (lane&15))*72 + kk*32 + k0]);
            acc[nt] = __builtin_amdgcn_mfma_f32_16x16x32_bf16(afr[kk], bfr, acc[nt], 0, 0, 0);
        }
    }
    __syncthreads();   // BtS dead -> epilogue buffer, stride 264 (16B-aligned rows)
    unsigned short* E = BtS;
    #pragma unroll
    for (int nt = 0; nt < 16; ++nt){
        #pragma unroll
        for (int rg = 0; rg < 4; ++rg){
            int epx = w*16 + (lane>>4)*4 + rg;
            int eo  = nt*16 + (lane&15);
            E[epx*264 + eo] = f2bu(acc[nt][rg]);
        }
    }
    __syncthreads();
    int spx = t & 63;
    size_t su = (size_t)uRp*258;
    uint4* ub = u + (size_t)bi*32*su + (size_t)(lr+1)*258 + (quarter*64 + spx + 1);
    int og = t >> 6;
    #pragma unroll
    for (int j = 0; j < 8; ++j){
        int od = og*8 + j;
        uint4 q4 = *reinterpret_cast<const uint4*>(&E[spx*264 + od*8]);
        ub[(size_t)od*su] = q4;
    }
}

// ---------------- K1b: depthwise 3x3 x2 + relu + channel-sum + fused h-g1x1 ----------------
// d1s layout: [508 planes (linear shuffled idx)][tR rows][256] u16 — dense coalesced stores.
// 1 oct per block (NCH=32 chunks).
__global__ __launch_bounds__(256) void k_dw(const uint4* __restrict__ u,
        const float* __restrict__ wDp, const float* __restrict__ whp1,
        unsigned short* __restrict__ d1s, float* __restrict__ Sp,
        int tr0, int trows, int ur0, int uRp, int tR, int nbat){
    int od = blockIdx.x & (NCH-1);
    int rb = blockIdx.x >> 5;
    int bi = rb / trows;
    int lr = rb - bi*trows;
    int grow = tr0 + lr;
    int xx = threadIdx.x;
    int lrow = grow - ur0;
    size_t su = (size_t)uRp*258;
    const uint4* up = u + (size_t)bi*32*su + (size_t)lrow*258 + xx + (size_t)od*su;
    size_t ps_d = (size_t)tR*256;
    unsigned short* dbs = d1s + (size_t)bi*508*ps_d + (size_t)lr*256 + xx;
    f32x2 P[8];
    #pragma unroll
    for (int j = 0; j < 8; ++j) P[j] = (f32x2){0.f, 0.f};
    #pragma unroll
    for (int q = 0; q < 9; ++q){
        uint4 rv = up[(q/3)*258 + (q%3)];
        f32x2 d0 = (f32x2){bflo(rv.x), bfhi(rv.x)};
        f32x2 d1v = (f32x2){bflo(rv.y), bfhi(rv.y)};
        f32x2 d2 = (f32x2){bflo(rv.z), bfhi(rv.z)};
        f32x2 d3 = (f32x2){bflo(rv.w), bfhi(rv.w)};
        const float* wq = wDp + (size_t)(16*od)*9 + q;
        P[0] += (f32x2){wq[0],   wq[18]}  * d0;
        P[1] += (f32x2){wq[9],   wq[27]}  * d0;
        P[2] += (f32x2){wq[36],  wq[54]}  * d1v;
        P[3] += (f32x2){wq[45],  wq[63]}  * d1v;
        P[4] += (f32x2){wq[72],  wq[90]}  * d2;
        P[5] += (f32x2){wq[81],  wq[99]}  * d2;
        P[6] += (f32x2){wq[108], wq[126]} * d3;
        P[7] += (f32x2){wq[117], wq[135]} * d3;
    }
    float ssum = 0.f;
    #pragma unroll
    for (int j = 0; j < 8; ++j){
        P[j].x = fmaxf(P[j].x, 0.f);
        P[j].y = fmaxf(P[j].y, 0.f);
        ssum += P[j].x + P[j].y;
    }
    // fused h-path first g1x1; o[4m..4m+3] = P[2m].x, P[2m+1].x, P[2m].y, P[2m+1].y
    int tqb = 4*od;
    #pragma unroll
    for (int m = 0; m < 4; ++m){
        int tq = tqb + m;
        if (tq < 127){
            float o0 = P[2*m].x, o1 = P[2*m+1].x, o2 = P[2*m].y, o3 = P[2*m+1].y;
            const float* w1 = whp1 + tq*16;
            #pragma unroll
            for (int oi = 0; oi < 4; ++oi){
                float d = fmaf(w1[oi*4+0], o0, fmaf(w1[oi*4+1], o1,
                          fmaf(w1[oi*4+2], o2, w1[oi*4+3]*o3)));
                int idx = 127*oi + tq;
                dbs[(size_t)idx*ps_d] = f2bu(d);
            }
        }
    }
    Sp[((size_t)(od*nbat + bi)*tR + lr)*256 + xx] = ssum * (1.f/9.f);
}

// ---------------- K2: sum chunks + 3x3 box -> padded Lm (f32) + Lpk (packed max/min bf16) ----------------
__global__ __launch_bounds__(256) void k_box(const float* __restrict__ Sp, float* __restrict__ Lm,
        unsigned int* __restrict__ Lpk,
        int lr0, int lrows, int tr0, int tR, int a, int lRp, int nbat){
    int bi = blockIdx.x / lrows;
    int lr = blockIdx.x - bi*lrows;
    int grow = lr0 + lr;
    int xx = threadIdx.x;
    int g0 = (grow-1 > 0 ? grow-1 : 0) - tr0, g1 = grow - tr0, g2 = (grow+1 < 255 ? grow+1 : 255) - tr0;
    int x0 = xx-1 > 0 ? xx-1 : 0, x2 = xx+1 < 255 ? xx+1 : 255;
    float s = 0.f;
    #pragma unroll 8
    for (int ch = 0; ch < NCH; ++ch){
        const float* Sb = Sp + ((size_t)(ch*nbat + bi)*tR)*256;
        s += Sb[g0*256+x0]+Sb[g0*256+xx]+Sb[g0*256+x2]
           + Sb[g1*256+x0]+Sb[g1*256+xx]+Sb[g1*256+x2]
           + Sb[g2*256+x0]+Sb[g2*256+xx]+Sb[g2*256+x2];
    }
    size_t o = (size_t)bi*lRp*258 + (size_t)(grow-a+1)*258 + xx + 1;
    Lm[o] = s;
    Lpk[o] = pk2c(fmaxf(s, 0.f), fminf(s, 0.f));
}

// ---------------- K3: fused h-finish + grouped 3x3 -> v, 8-row tiles, rolling registers ----------------
__global__ __launch_bounds__(256) void k_mov(const unsigned short* __restrict__ d1s,
     const float* __restrict__ Lm, const unsigned int* __restrict__ Lpk,
     const float* __restrict__ whp2, const float* __restrict__ ahp1s,
     const unsigned int* __restrict__ WPNL, const unsigned int* __restrict__ WPNH,
     const unsigned int* __restrict__ WLDpk, const unsigned int* __restrict__ WHDpk,
     unsigned int* __restrict__ v,
     int a, int orows, int tr0, int tR, int lRp){
    __shared__ uint2 h2t[10][258];
    int g = blockIdx.x % 127;
    int rest = blockIdx.x / 127;
    int ntiles = orows >> 3;
    int ti = rest % ntiles;
    int bi = rest / ntiles;
    int px = threadIdx.x;
    int row0 = a + ti*8;
    // ---- phase 1: build h2 tile (10 rows) in LDS ----
    size_t ps_d = (size_t)tR*256;
    const unsigned short* dp0 = d1s + ((size_t)bi*508 + 4*g+0)*ps_d;
    const unsigned short* dp1 = d1s + ((size_t)bi*508 + 4*g+1)*ps_d;
    const unsigned short* dp2 = d1s + ((size_t)bi*508 + 4*g+2)*ps_d;
    const unsigned short* dp3 = d1s + ((size_t)bi*508 + 4*g+3)*ps_d;
    const float* Lb = Lm + (size_t)bi*lRp*258;
    float as0 = ahp1s[4*g], as1 = ahp1s[4*g+1], as2 = ahp1s[4*g+2], as3 = ahp1s[4*g+3];
    float w2r[16];
    #pragma unroll
    for (int i = 0; i < 16; ++i) w2r[i] = whp2[g*16 + i];
    #pragma unroll
    for (int rr = 0; rr < 10; ++rr){
        int gr = row0 - 1 + rr;
        uint2 hv; hv.x = 0u; hv.y = 0u;
        if (gr >= 0 && gr < 256){
            size_t ro = (size_t)(gr - tr0)*256 + px;
            float d0 = bfu(dp0[ro]);
            float d1 = bfu(dp1[ro]);
            float d2 = bfu(dp2[ro]);
            float d3 = bfu(dp3[ro]);
            float Lv = Lb[(size_t)(gr - a + 1)*258 + px + 1];
            float h0 = fmaxf(fmaf(-Lv, as0, d0), 0.f);
            float h1 = fmaxf(fmaf(-Lv, as1, d1), 0.f);
            float hm2 = fmaxf(fmaf(-Lv, as2, d2), 0.f);
            float h3 = fmaxf(fmaf(-Lv, as3, d3), 0.f);
            float a0 = fmaf(w2r[0], h0, fmaf(w2r[1], h1, fmaf(w2r[2], hm2, w2r[3]*h3)));
            float a1 = fmaf(w2r[4], h0, fmaf(w2r[5], h1, fmaf(w2r[6], hm2, w2r[7]*h3)));
            float a2 = fmaf(w2r[8], h0, fmaf(w2r[9], h1, fmaf(w2r[10], hm2, w2r[11]*h3)));
            float a3 = fmaf(w2r[12], h0, fmaf(w2r[13], h1, fmaf(w2r[14], hm2, w2r[15]*h3)));
            hv.x = pk2c(a0, a1);
            hv.y = pk2c(a2, a3);
        }
        h2t[rr][px+1] = hv;
    }
    if (px < 10){ uint2 z; z.x = 0u; z.y = 0u; h2t[px][0] = z; h2t[px][257] = z; }
    __syncthreads();
    // ---- block-uniform tables ----
    s16x2 WPl[9], WPh[9];
    #pragma unroll
    for (int q = 0; q < 9; ++q){
        WPl[q] = __builtin_bit_cast(s16x2, WPNL[g*9+q]);
        WPh[q] = __builtin_bit_cast(s16x2, WPNH[g*9+q]);
    }
    bool lbr = (g >= 63), hbr = (g <= 63);
    s16x2 WDl[18], WDh[18];
    #pragma unroll
    for (int i = 0; i < 18; ++i){
        WDl[i] = __builtin_bit_cast(s16x2, WLDpk[g*18+i]);
        WDh[i] = __builtin_bit_cast(s16x2, WHDpk[g*18+i]);
    }
    // ---- phase 2: rolling registers over 8 output rows ----
    size_t ps = (size_t)orows*256;
    unsigned int* vb = v + ((size_t)bi*128 + g)*ps + (size_t)(ti*8)*256 + px;
    const unsigned int* Lq = Lpk + (size_t)bi*lRp*258 + (size_t)(ti*8)*258 + px;   // tap row base
    s16x2 lq[3][3];
    uint2 ta[3][3];
    #pragma unroll
    for (int rr = 0; rr < 2; ++rr){
        #pragma unroll
        for (int c = 0; c < 3; ++c){
            lq[rr][c] = __builtin_bit_cast(s16x2, Lq[(size_t)rr*258 + c]);
            ta[rr][c] = h2t[rr][px + c];
        }
    }
    #pragma unroll
    for (int r = 0; r < 8; ++r){
        #pragma unroll
        for (int c = 0; c < 3; ++c){
            lq[2][c] = __builtin_bit_cast(s16x2, Lq[(size_t)(r+2)*258 + c]);
            ta[2][c] = h2t[r+2][px + c];
        }
        float sl0 = 0.f, sl1 = 0.f, sh0 = 0.f, sh1 = 0.f;
        #pragma unroll
        for (int dy = 0; dy < 3; ++dy){
            #pragma unroll
            for (int dx = 0; dx < 3; ++dx){
                int q = dy*3 + dx;
                if (q & 1){ sl1 = DOT2B(lq[dy][dx], WPl[q], sl1); sh1 = DOT2B(lq[dy][dx], WPh[q], sh1); }
                else      { sl0 = DOT2B(lq[dy][dx], WPl[q], sl0); sh0 = DOT2B(lq[dy][dx], WPh[q], sh0); }
            }
        }
        if (lbr){
            #pragma unroll
            for (int dy = 0; dy < 3; ++dy){
                #pragma unroll
                for (int dx = 0; dx < 3; ++dx){
                    int q = dy*3 + dx;
                    uint2 tv = ta[dy][dx];
                    sl0 = DOT2B(__builtin_bit_cast(s16x2, tv.x), WDl[2*q],   sl0);
                    sl1 = DOT2B(__builtin_bit_cast(s16x2, tv.y), WDl[2*q+1], sl1);
                }
            }
        }
        if (hbr){
            #pragma unroll
            for (int dy = 0; dy < 3; ++dy){
                #pragma unroll
                for (int dx = 0; dx < 3; ++dx){
                    int q = dy*3 + dx;
                    uint2 tv = ta[dy][dx];
                    sh0 = DOT2B(__builtin_bit_cast(s16x2, tv.x), WDh[2*q],   sh0);
                    sh1 = DOT2B(__builtin_bit_cast(s16x2, tv.y), WDh[2*q+1], sh1);
                }
            }
        }
        vb[(size_t)r*256] = pk2c(fmaxf(sl0+sl1, 0.f), fmaxf(sh0+sh1, 0.f));
        if (g == 126) vb[(size_t)r*256 + ps] = 0u;   // zero pad plane 127
        #pragma unroll
        for (int c = 0; c < 3; ++c){
            ta[0][c] = ta[1][c]; ta[1][c] = ta[2][c];
            lq[0][c] = lq[1][c]; lq[1][c] = lq[2][c];
        }
    }
}

// ---------------- K4: out = v @ BtP^T + x via MFMA, fused residual ----------------
__global__ __launch_bounds__(256) void k_proj(const unsigned int* __restrict__ v,
        const unsigned short* __restrict__ BtP, const float* __restrict__ x,
        float* __restrict__ out, int b0, int a, int orows){
    __shared__ float EoS[256*49];            // 50176 B; Bt overlays first 26112 B
    unsigned short* Bt = (unsigned short*)EoS;   // [48 n][136 u16]
    int t = threadIdx.x;
    for (int i = t; i < 48*256; i += 256){
        int n = i >> 8, k = i & 255;
        Bt[n*136 + k] = BtP[i];
    }
    int bi = blockIdx.x / orows;
    int lr = blockIdx.x - bi*orows;
    int b = b0 + bi;
    size_t ps = (size_t)orows*256;
    const unsigned int* vb = v + (size_t)bi*128*ps + (size_t)lr*256;
    int lane = t & 63, w = t >> 6;
    int pxl = w*64;
    __syncthreads();
    f32x4 acc[4][3];
    #pragma unroll
    for (int m = 0; m < 4; ++m)
        #pragma unroll
        for (int nt = 0; nt < 3; ++nt) acc[m][nt] = (f32x4){0.f,0.f,0.f,0.f};
    #pragma unroll
    for (int ch = 0; ch < 4; ++ch){
        bf16x8 bfr[3][2];
        #pragma unroll
        for (int nt = 0; nt < 3; ++nt)
            #pragma unroll
            for (int kk = 0; kk < 2; ++kk)
                bfr[nt][kk] = *reinterpret_cast<const bf16x8*>(
                    &Bt[(nt*16 + (lane&15))*136 + ch*64 + kk*32 + (lane>>4)*8]);
        #pragma unroll
        for (int m = 0; m < 4; ++m){
            int px = pxl + m*16 + (lane & 15);
            #pragma unroll
            for (int kk = 0; kk < 2; ++kk){
                int pl0 = ch*32 + kk*16 + (lane>>4)*4;
                unsigned int p0 = vb[(size_t)(pl0+0)*ps + px];
                unsigned int p1 = vb[(size_t)(pl0+1)*ps + px];
                unsigned int p2 = vb[(size_t)(pl0+2)*ps + px];
                unsigned int p3 = vb[(size_t)(pl0+3)*ps + px];
                bf16x8 af;
                af[0]=(short)(p0&0xffff); af[1]=(short)(p0>>16);
                af[2]=(short)(p1&0xffff); af[3]=(short)(p1>>16);
                af[4]=(short)(p2&0xffff); af[5]=(short)(p2>>16);
                af[6]=(short)(p3&0xffff); af[7]=(short)(p3>>16);
                #pragma unroll
                for (int nt = 0; nt < 3; ++nt)
                    acc[m][nt] = __builtin_amdgcn_mfma_f32_16x16x32_bf16(af, bfr[nt][kk], acc[m][nt], 0, 0, 0);
            }
        }
    }
    __syncthreads();   // Bt dead -> epilogue buffer
    #pragma unroll
    for (int m = 0; m < 4; ++m){
        #pragma unroll
        for (int nt = 0; nt < 3; ++nt){
            #pragma unroll
            for (int rg = 0; rg < 4; ++rg){
                int epx = pxl + m*16 + (lane>>4)*4 + rg;
                int eo  = nt*16 + (lane&15);
                EoS[epx*49 + eo] = acc[m][nt][rg];
            }
        }
    }
    __syncthreads();
    int grow = a + lr;
    const float* xb = x + (size_t)b*48*HW + (size_t)grow*256 + t;
    float* ob = out + (size_t)b*48*HW + (size_t)grow*256 + t;
    #pragma unroll
    for (int o = 0; o < 48; ++o)
        ob[(size_t)o*HW] = EoS[t*49 + o] + xb[(size_t)o*HW];
}

extern "C" void kernel_launch(void* const* d_in, const int* in_sizes, int n_in,
                              void* d_out, int out_size, void* d_ws, size_t ws_size,
                              hipStream_t stream){
    const float* x    = (const float*)d_in[0];
    const float* winP = (const float*)d_in[1];
    const float* winD = (const float*)d_in[2];
    const float* wlp1 = (const float*)d_in[3];
    const float* whp1 = (const float*)d_in[4];
    const float* wlp2 = (const float*)d_in[5];
    const float* whp2 = (const float*)d_in[6];
    const float* wld  = (const float*)d_in[7];
    const float* whd  = (const float*)d_in[8];
    const float* wout = (const float*)d_in[9];
    float* out = (float*)d_out;

    char* ws = (char*)d_ws;
    size_t off = 0;
    auto alloc = [&](size_t bytes)->char*{
        char* pp = ws + off; off += (bytes + 255) & ~(size_t)255; return pp;
    };
    auto A = [](size_t bytes)->size_t{ return (bytes + 255) & ~(size_t)255; };

    float* ahp1s = (float*)alloc(508*4);
    float* cpG = (float*)alloc(508*4);
    float* cnG = (float*)alloc(508*4);
    unsigned int* WPNL  = (unsigned int*)alloc(127*9*4);
    unsigned int* WPNH  = (unsigned int*)alloc(127*9*4);
    unsigned int* WLDpk = (unsigned int*)alloc(127*18*4);
    unsigned int* WHDpk = (unsigned int*)alloc(127*18*4);
    float* wDp  = (float*)alloc(512*9*4);
    unsigned short* WPb = (unsigned short*)alloc(256*64*2);
    unsigned short* BtP = (unsigned short*)alloc(48*256*2);

    // ladder: Hb must be a multiple of 8 (k_mov tiles)
    const int cfgs[6][2] = {{256,2},{128,2},{64,2},{64,1},{32,1},{16,1}};
    int Hb = 16, nbat = 1;
    for (int ci = 0; ci < 6; ++ci){
        int hb = cfgs[ci][0], nb = cfgs[ci][1];
        int uRr = hb+6 < 256 ? hb+6 : 256;
        int tRr = hb+4 < 256 ? hb+4 : 256;
        size_t need = off;
        need += A((size_t)nb*32*(uRr+2)*258*16);   // u (padded oct layout; v aliases it)
        need += A((size_t)nb*508*tRr*256*2);       // d1s (508 u16 planes)
        need += A((size_t)nb*NCH*tRr*256*4);       // Sp
        need += A((size_t)nb*(hb+2)*258*4);        // Lm (padded)
        need += A((size_t)nb*(hb+2)*258*4);        // Lpk (padded)
        if (need <= ws_size){ Hb = hb; nbat = nb; break; }
    }
    int uR = Hb+6 < 256 ? Hb+6 : 256;
    int tR = Hb+4 < 256 ? Hb+4 : 256;
    int uRp = uR + 2;
    int lRp = Hb + 2;
    uint4* u   = (uint4*)alloc((size_t)nbat*32*uRp*258*16);
    unsigned short* d1s = (unsigned short*)alloc((size_t)nbat*508*tR*256*2);
    float* Sp = (float*)alloc((size_t)nbat*NCH*tR*256*4);
    float* Lm = (float*)alloc((size_t)nbat*lRp*258*4);
    unsigned int* Lpk = (unsigned int*)alloc((size_t)nbat*lRp*258*4);
    // v aliases u: u is dead after k_dw; per-band order pconv->dw->mov->proj keeps it safe.
    unsigned int* v = (unsigned int*)u;

    k_coef1<<<1, 512, 0, stream>>>(wlp1, whp1, wlp2, ahp1s, cpG, cnG);
    k_coef2<<<64, 256, 0, stream>>>(wld, whd, winP, winD, wout, cpG, cnG,
                                    WPNL, WPNH, WLDpk, WHDpk, wDp, WPb, BtP);

    for (int b0 = 0; b0 < 2; b0 += nbat){
        for (int a = 0; a < 256; a += Hb){
            int ur0 = a-3 > 0 ? a-3 : 0;  int ur1 = a+Hb+3 < 256 ? a+Hb+3 : 256;
            int tr0 = a-2 > 0 ? a-2 : 0;  int tr1 = a+Hb+2 < 256 ? a+Hb+2 : 256;
            int lr0 = a-1 > 0 ? a-1 : 0;  int lr1 = a+Hb+1 < 256 ? a+Hb+1 : 256;
            int urows = ur1-ur0, trows = tr1-tr0, lrows = lr1-lr0;
            int orows = (a+Hb < 256 ? a+Hb : 256) - a;
            k_padU<<<nbat*32 + nbat, 256, 0, stream>>>(u, Lm, Lpk, uRp, lRp, nbat,
                                                       a == 0, a + Hb >= 256);
            k_pconv<<<nbat*urows*4, 256, 0, stream>>>(x, WPb, u, b0, ur0, urows, uRp);
            k_dw  <<<nbat*trows*NCH, 256, 0, stream>>>(u, wDp, whp1, d1s, Sp, tr0, trows, ur0, uRp, tR, nbat);
            k_box <<<nbat*lrows, 256, 0, stream>>>(Sp, Lm, Lpk, lr0, lrows, tr0, tR, a, lRp, nbat);
            k_mov <<<nbat*(orows>>3)*127, 256, 0, stream>>>(d1s, Lm, Lpk, whp2, ahp1s,
                                                            WPNL, WPNH, WLDpk, WHDpk, v,
                                                            a, orows, tr0, tR, lRp);
            k_proj<<<nbat*orows, 256, 0, stream>>>(v, BtP, x, out, b0, a, orows);
        }
    }
}

// Round 16
// 162.061 us; speedup vs baseline: 1.3080x; 1.3080x over previous
//
#include <hip/hip_runtime.h>
#include <hip/hip_bf16.h>

#define HW 65536
#define NCH 16   // channel chunks in k_dw (2 octs each)

typedef __attribute__((ext_vector_type(8))) short bf16x8;
typedef __attribute__((ext_vector_type(4))) float f32x4;
typedef __attribute__((ext_vector_type(2))) float f32x2;
typedef __attribute__((ext_vector_type(2))) short s16x2;

__device__ __forceinline__ float bfu(unsigned short u){
    return __uint_as_float(((unsigned int)u) << 16);
}
__device__ __forceinline__ float bflo(unsigned int u){
    return __uint_as_float(u << 16);
}
__device__ __forceinline__ float bfhi(unsigned int u){
    return __uint_as_float(u & 0xffff0000u);
}
__device__ __forceinline__ unsigned short f2bu(float f){
    return __builtin_bit_cast(unsigned short, __float2bfloat16(f));
}
__device__ __forceinline__ unsigned int pk2(float a, float b){
    return (unsigned int)f2bu(a) | ((unsigned int)f2bu(b) << 16);
}
// v_cvt_pk_bf16_f32: packs (a,b) -> (lo=bf16(a), hi=bf16(b)), RTNE. No builtin on gfx950.
__device__ __forceinline__ unsigned int pk2c(float a, float b){
    unsigned int r;
    asm("v_cvt_pk_bf16_f32 %0, %1, %2" : "=v"(r) : "v"(a), "v"(b));
    return r;
}

#if __has_builtin(__builtin_amdgcn_fdot2_f32_bf16)
__device__ __forceinline__ float DOT2B(s16x2 a, s16x2 b, float c){
    return __builtin_amdgcn_fdot2_f32_bf16(a, b, c, false);
}
#else
__device__ __forceinline__ float DOT2B(s16x2 a, s16x2 b, float c){
    return fmaf(bfu((unsigned short)a.x), bfu((unsigned short)b.x),
           fmaf(bfu((unsigned short)a.y), bfu((unsigned short)b.y), c));
}
#endif

// ---------------- K0a: sequential coefficient core (1 block) ----------------
__global__ void k_coef1(const float* __restrict__ wlp1, const float* __restrict__ whp1,
                        const float* __restrict__ wlp2,
                        float* __restrict__ ahp1s,
                        float* __restrict__ cpG, float* __restrict__ cnG){
    __shared__ float aL[508], ah[508];
    int t = threadIdx.x;
    if (t < 508){
        int g = t >> 2, o = t & 3;
        float s = 0.f, s2 = 0.f;
        for (int i = 0; i < 4; ++i){ s += wlp1[g*16 + o*4 + i]; s2 += whp1[g*16 + o*4 + i]; }
        aL[t] = s; ah[t] = s2;
    }
    __syncthreads();
    if (t < 508){
        int g = t >> 2, o = t & 3;
        float p = 0.f, n = 0.f;
        for (int k = 0; k < 4; ++k){
            int idx = 4*g + k;                    // shuffled position
            int inv = (idx % 127)*4 + idx/127;    // original channel
            float av = aL[inv];
            float w2 = wlp2[g*16 + o*4 + k];
            p += w2 * fmaxf(av, 0.f);
            n += w2 * fminf(av, 0.f);
        }
        cpG[t] = p; cnG[t] = n;
        int inv = (t % 127)*4 + t/127;
        ahp1s[t] = ah[inv];
    }
}

// ---------------- K0b: parallel table fills (64 blocks, grid-strided) ----------------
__global__ void k_coef2(const float* __restrict__ wld, const float* __restrict__ whd,
                        const float* __restrict__ winP, const float* __restrict__ winD,
                        const float* __restrict__ wout,
                        const float* __restrict__ cp, const float* __restrict__ cn,
                        unsigned int* __restrict__ WPNL, unsigned int* __restrict__ WPNH,
                        unsigned int* __restrict__ WLDpk, unsigned int* __restrict__ WHDpk,
                        float* __restrict__ wDp,
                        unsigned short* __restrict__ WPb, unsigned short* __restrict__ BtP){
    int t0 = blockIdx.x*256 + threadIdx.x;
    int str = gridDim.x*256;
    // analytic tables, packed (pos,neg) bf16 pairs
    for (int idx = t0; idx < 127*9; idx += str){
        int g = idx/9, q = idx%9;
        float lp=0.f, ln=0.f, hp=0.f, hn=0.f;
        for (int i = 0; i < 4; ++i){
            int ch = 4*g + i;
            if (ch < 254){ float w = wld[g*36 + i*9 + q]; lp += w*cp[ch]; ln += w*cn[ch]; }
            else         { float w = whd[g*36 + i*9 + q]; hp += w*cp[ch]; hn += w*cn[ch]; }
        }
        WPNL[idx] = pk2(lp, ln);
        WPNH[idx] = pk2(hp, hn);
    }
    // conv tables, packed channel-pair bf16 weights (masked to h2-sourced channels)
    for (int idx = t0; idx < 127*18; idx += str){
        int g = idx/18, r = idx%18; int q = r >> 1, hp_ = r & 1;
        int c0 = 4*g + 2*hp_, c1 = c0 + 1;
        float wl0 = (c0 >= 254) ? wld[g*36 + (2*hp_)*9 + q]   : 0.f;
        float wl1 = (c1 >= 254) ? wld[g*36 + (2*hp_+1)*9 + q] : 0.f;
        float wh0 = (c0 <  254) ? whd[g*36 + (2*hp_)*9 + q]   : 0.f;
        float wh1 = (c1 <  254) ? whd[g*36 + (2*hp_+1)*9 + q] : 0.f;
        WLDpk[idx] = pk2(wl0, wl1);
        WHDpk[idx] = pk2(wh0, wh1);
    }
    // wDp: [512 tch][9], zero-padded winD (508x9)
    for (int idx = t0; idx < 512*9; idx += str){
        int ch = idx/9, q = idx - ch*9;
        wDp[idx] = (ch < 508) ? winD[ch*9 + q] : 0.f;
    }
    // WPb: [256 o][64 k] bf16, zero-padded winP
    for (int idx = t0; idx < 256*64; idx += str){
        int o = idx >> 6, k = idx & 63;
        float vv = (o < 254 && k < 48) ? winP[o*48 + k] : 0.f;
        WPb[idx] = f2bu(vv);
    }
    // BtP: [48 n][256 k] bf16; k=2g -> wout[n][g] (l), k=2g+1 -> wout[n][127+g] (h)
    for (int idx = t0; idx < 48*256; idx += str){
        int n = idx >> 8, k = idx & 255;
        int g = k >> 1;
        float vv = (g < 127) ? ((k & 1) ? wout[n*254 + 127 + g] : wout[n*254 + g]) : 0.f;
        BtP[idx] = f2bu(vv);
    }
}

// ---------------- per-band border zeroing ----------------
__global__ void k_padU(uint4* __restrict__ u, float* __restrict__ Lm, unsigned int* __restrict__ Lpk,
                       int uRp, int lRp, int nbat, int zeroTop, int zeroBot){
    int p = blockIdx.x, t = threadIdx.x;
    int nu = nbat*32;
    if (p < nu){
        uint4* pl = u + (size_t)p*uRp*258;
        uint4 z = make_uint4(0,0,0,0);
        for (int i = t; i < 258; i += 256){ pl[i] = z; pl[(size_t)(uRp-1)*258 + i] = z; }
        for (int r = t; r < uRp; r += 256){ pl[(size_t)r*258] = z; pl[(size_t)r*258 + 257] = z; }
    } else {
        float* pl = Lm + (size_t)(p-nu)*lRp*258;
        unsigned int* pk = Lpk + (size_t)(p-nu)*lRp*258;
        if (zeroTop) for (int i = t; i < 258; i += 256){ pl[i] = 0.f; pk[i] = 0u; }
        if (zeroBot) for (int i = t; i < 258; i += 256){ pl[(size_t)(lRp-1)*258 + i] = 0.f; pk[(size_t)(lRp-1)*258 + i] = 0u; }
        for (int r = t; r < lRp; r += 256){
            pl[(size_t)r*258] = 0.f; pl[(size_t)r*258 + 257] = 0.f;
            pk[(size_t)r*258] = 0u;  pk[(size_t)r*258 + 257] = 0u;
        }
    }
}

// ---------------- K1a: u = w_inP @ x (1x1 48->254) via MFMA, padded oct layout ----------------
__global__ __launch_bounds__(256) void k_pconv(const float* __restrict__ x,
        const unsigned short* __restrict__ WPb, uint4* __restrict__ u,
        int b0, int ur0, int urows, int uRp){
    __shared__ unsigned short BtS[256*72];   // 36864 B; epilogue overlays [64px][264 u16]=33792 B
    int t = threadIdx.x;
    for (int i = t; i < 256*64; i += 256){
        int o = i >> 6, k = i & 63;
        BtS[o*72 + k] = WPb[i];
    }
    int bpb = urows*4;
    int bi = blockIdx.x / bpb;
    int r  = blockIdx.x - bi*bpb;
    int lr = r >> 2, quarter = r & 3;
    int b = b0 + bi;
    int grow = ur0 + lr;
    const float* xb = x + (size_t)b*48*HW + (size_t)grow*256 + quarter*64;
    int w = t >> 6, lane = t & 63;
    int px = w*16 + (lane & 15);
    int k0 = (lane >> 4)*8;
    bf16x8 afr[2];
    #pragma unroll
    for (int kk = 0; kk < 2; ++kk){
        #pragma unroll
        for (int j = 0; j < 8; ++j){
            int k = kk*32 + k0 + j;
            float vv = (k < 48) ? xb[(size_t)k*HW + px] : 0.f;
            afr[kk][j] = (short)f2bu(vv);
        }
    }
    __syncthreads();
    f32x4 acc[16];
    #pragma unroll
    for (int nt = 0; nt < 16; ++nt) acc[nt] = (f32x4){0.f,0.f,0.f,0.f};
    #pragma unroll
    for (int kk = 0; kk < 2; ++kk){
        #pragma unroll
        for (int nt = 0; nt < 16; ++nt){
            bf16x8 bfr = *reinterpret_cast<const bf16x8*>(&BtS[(nt*16 + (lane&15))*72 + kk*32 + k0]);
            acc[nt] = __builtin_amdgcn_mfma_f32_16x16x32_bf16(afr[kk], bfr, acc[nt], 0, 0, 0);
        }
    }
    __syncthreads();   // BtS dead -> epilogue buffer, stride 264 (16B-aligned rows)
    unsigned short* E = BtS;
    #pragma unroll
    for (int nt = 0; nt < 16; ++nt){
        #pragma unroll
        for (int rg = 0; rg < 4; ++rg){
            int epx = w*16 + (lane>>4)*4 + rg;
            int eo  = nt*16 + (lane&15);
            E[epx*264 + eo] = f2bu(acc[nt][rg]);
        }
    }
    __syncthreads();
    int spx = t & 63;
    size_t su = (size_t)uRp*258;
    uint4* ub = u + (size_t)bi*32*su + (size_t)(lr+1)*258 + (quarter*64 + spx + 1);
    int og = t >> 6;
    #pragma unroll
    for (int j = 0; j < 8; ++j){
        int od = og*8 + j;
        uint4 q4 = *reinterpret_cast<const uint4*>(&E[spx*264 + od*8]);
        ub[(size_t)od*su] = q4;
    }
}

// ---------------- K1b: depthwise 3x3 x2 + relu + channel-sum + fused h-g1x1 ----------------
// d1s layout: [508 planes (linear shuffled idx)][tR rows][256] u16 — dense coalesced stores.
__global__ __launch_bounds__(256) void k_dw(const uint4* __restrict__ u,
        const float* __restrict__ wDp, const float* __restrict__ whp1,
        unsigned short* __restrict__ d1s, float* __restrict__ Sp,
        int tr0, int trows, int ur0, int uRp, int tR, int nbat){
    int chunk = blockIdx.x & (NCH-1);
    int rb = blockIdx.x >> 4;
    int bi = rb / trows;
    int lr = rb - bi*trows;
    int grow = tr0 + lr;
    int xx = threadIdx.x;
    int lrow = grow - ur0;
    size_t su = (size_t)uRp*258;
    const uint4* ubase = u + (size_t)bi*32*su + (size_t)lrow*258 + xx;
    size_t ps_d = (size_t)tR*256;
    unsigned short* dbs = d1s + (size_t)bi*508*ps_d + (size_t)lr*256 + xx;
    float ssum = 0.f;
    int od0 = chunk*2;
    for (int od = od0; od < od0+2; ++od){
        const uint4* up = ubase + (size_t)od*su;
        f32x2 P[8];
        #pragma unroll
        for (int j = 0; j < 8; ++j) P[j] = (f32x2){0.f, 0.f};
        #pragma unroll
        for (int q = 0; q < 9; ++q){
            uint4 rv = up[(q/3)*258 + (q%3)];
            f32x2 d0 = (f32x2){bflo(rv.x), bfhi(rv.x)};
            f32x2 d1v = (f32x2){bflo(rv.y), bfhi(rv.y)};
            f32x2 d2 = (f32x2){bflo(rv.z), bfhi(rv.z)};
            f32x2 d3 = (f32x2){bflo(rv.w), bfhi(rv.w)};
            const float* wq = wDp + (size_t)(16*od)*9 + q;
            P[0] += (f32x2){wq[0],   wq[18]}  * d0;
            P[1] += (f32x2){wq[9],   wq[27]}  * d0;
            P[2] += (f32x2){wq[36],  wq[54]}  * d1v;
            P[3] += (f32x2){wq[45],  wq[63]}  * d1v;
            P[4] += (f32x2){wq[72],  wq[90]}  * d2;
            P[5] += (f32x2){wq[81],  wq[99]}  * d2;
            P[6] += (f32x2){wq[108], wq[126]} * d3;
            P[7] += (f32x2){wq[117], wq[135]} * d3;
        }
        // relu + channel-sum
        #pragma unroll
        for (int j = 0; j < 8; ++j){
            P[j].x = fmaxf(P[j].x, 0.f);
            P[j].y = fmaxf(P[j].y, 0.f);
            ssum += P[j].x + P[j].y;
        }
        // fused h-path first g1x1; o[4m..4m+3] = P[2m].x, P[2m+1].x, P[2m].y, P[2m+1].y
        int tqb = 4*od;
        #pragma unroll
        for (int m = 0; m < 4; ++m){
            int tq = tqb + m;
            if (tq < 127){
                float o0 = P[2*m].x, o1 = P[2*m+1].x, o2 = P[2*m].y, o3 = P[2*m+1].y;
                const float* w1 = whp1 + tq*16;
                #pragma unroll
                for (int oi = 0; oi < 4; ++oi){
                    float d = fmaf(w1[oi*4+0], o0, fmaf(w1[oi*4+1], o1,
                              fmaf(w1[oi*4+2], o2, w1[oi*4+3]*o3)));
                    int idx = 127*oi + tq;
                    dbs[(size_t)idx*ps_d] = f2bu(d);
                }
            }
        }
    }
    Sp[((size_t)(chunk*nbat + bi)*tR + lr)*256 + xx] = ssum * (1.f/9.f);
}

// ---------------- K2: sum chunks + 3x3 box -> padded Lm (f32) + Lpk (packed max/min bf16) ----------------
__global__ __launch_bounds__(256) void k_box(const float* __restrict__ Sp, float* __restrict__ Lm,
        unsigned int* __restrict__ Lpk,
        int lr0, int lrows, int tr0, int tR, int a, int lRp, int nbat){
    int bi = blockIdx.x / lrows;
    int lr = blockIdx.x - bi*lrows;
    int grow = lr0 + lr;
    int xx = threadIdx.x;
    int g0 = (grow-1 > 0 ? grow-1 : 0) - tr0, g1 = grow - tr0, g2 = (grow+1 < 255 ? grow+1 : 255) - tr0;
    int x0 = xx-1 > 0 ? xx-1 : 0, x2 = xx+1 < 255 ? xx+1 : 255;
    float s = 0.f;
    for (int ch = 0; ch < NCH; ++ch){
        const float* Sb = Sp + ((size_t)(ch*nbat + bi)*tR)*256;
        s += Sb[g0*256+x0]+Sb[g0*256+xx]+Sb[g0*256+x2]
           + Sb[g1*256+x0]+Sb[g1*256+xx]+Sb[g1*256+x2]
           + Sb[g2*256+x0]+Sb[g2*256+xx]+Sb[g2*256+x2];
    }
    size_t o = (size_t)bi*lRp*258 + (size_t)(grow-a+1)*258 + xx + 1;
    Lm[o] = s;
    Lpk[o] = pk2c(fmaxf(s, 0.f), fminf(s, 0.f));
}

// ---------------- K3: fused h-finish + grouped 3x3 -> v, 8-row tiles, rolling registers ----------------
__global__ __launch_bounds__(256) void k_mov(const unsigned short* __restrict__ d1s,
     const float* __restrict__ Lm, const unsigned int* __restrict__ Lpk,
     const float* __restrict__ whp2, const float* __restrict__ ahp1s,
     const unsigned int* __restrict__ WPNL, const unsigned int* __restrict__ WPNH,
     const unsigned int* __restrict__ WLDpk, const unsigned int* __restrict__ WHDpk,
     unsigned int* __restrict__ v,
     int a, int orows, int tr0, int tR, int lRp){
    __shared__ uint2 h2t[10][258];
    int g = blockIdx.x % 127;
    int rest = blockIdx.x / 127;
    int ntiles = orows >> 3;
    int ti = rest % ntiles;
    int bi = rest / ntiles;
    int px = threadIdx.x;
    int row0 = a + ti*8;
    // ---- phase 1: build h2 tile (10 rows) in LDS ----
    size_t ps_d = (size_t)tR*256;
    const unsigned short* dp0 = d1s + ((size_t)bi*508 + 4*g+0)*ps_d;
    const unsigned short* dp1 = d1s + ((size_t)bi*508 + 4*g+1)*ps_d;
    const unsigned short* dp2 = d1s + ((size_t)bi*508 + 4*g+2)*ps_d;
    const unsigned short* dp3 = d1s + ((size_t)bi*508 + 4*g+3)*ps_d;
    const float* Lb = Lm + (size_t)bi*lRp*258;
    float as0 = ahp1s[4*g], as1 = ahp1s[4*g+1], as2 = ahp1s[4*g+2], as3 = ahp1s[4*g+3];
    float w2r[16];
    #pragma unroll
    for (int i = 0; i < 16; ++i) w2r[i] = whp2[g*16 + i];
    #pragma unroll
    for (int rr = 0; rr < 10; ++rr){
        int gr = row0 - 1 + rr;
        uint2 hv; hv.x = 0u; hv.y = 0u;
        if (gr >= 0 && gr < 256){
            size_t ro = (size_t)(gr - tr0)*256 + px;
            float d0 = bfu(dp0[ro]);
            float d1 = bfu(dp1[ro]);
            float d2 = bfu(dp2[ro]);
            float d3 = bfu(dp3[ro]);
            float Lv = Lb[(size_t)(gr - a + 1)*258 + px + 1];
            float h0 = fmaxf(fmaf(-Lv, as0, d0), 0.f);
            float h1 = fmaxf(fmaf(-Lv, as1, d1), 0.f);
            float hm2 = fmaxf(fmaf(-Lv, as2, d2), 0.f);
            float h3 = fmaxf(fmaf(-Lv, as3, d3), 0.f);
            float a0 = fmaf(w2r[0], h0, fmaf(w2r[1], h1, fmaf(w2r[2], hm2, w2r[3]*h3)));
            float a1 = fmaf(w2r[4], h0, fmaf(w2r[5], h1, fmaf(w2r[6], hm2, w2r[7]*h3)));
            float a2 = fmaf(w2r[8], h0, fmaf(w2r[9], h1, fmaf(w2r[10], hm2, w2r[11]*h3)));
            float a3 = fmaf(w2r[12], h0, fmaf(w2r[13], h1, fmaf(w2r[14], hm2, w2r[15]*h3)));
            hv.x = pk2c(a0, a1);
            hv.y = pk2c(a2, a3);
        }
        h2t[rr][px+1] = hv;
    }
    if (px < 10){ uint2 z; z.x = 0u; z.y = 0u; h2t[px][0] = z; h2t[px][257] = z; }
    __syncthreads();
    // ---- block-uniform tables ----
    s16x2 WPl[9], WPh[9];
    #pragma unroll
    for (int q = 0; q < 9; ++q){
        WPl[q] = __builtin_bit_cast(s16x2, WPNL[g*9+q]);
        WPh[q] = __builtin_bit_cast(s16x2, WPNH[g*9+q]);
    }
    bool lbr = (g >= 63), hbr = (g <= 63);
    s16x2 WDl[18], WDh[18];
    #pragma unroll
    for (int i = 0; i < 18; ++i){
        WDl[i] = __builtin_bit_cast(s16x2, WLDpk[g*18+i]);
        WDh[i] = __builtin_bit_cast(s16x2, WHDpk[g*18+i]);
    }
    // ---- phase 2: rolling registers over 8 output rows ----
    size_t ps = (size_t)orows*256;
    unsigned int* vb = v + ((size_t)bi*128 + g)*ps + (size_t)(ti*8)*256 + px;
    const unsigned int* Lq = Lpk + (size_t)bi*lRp*258 + (size_t)(ti*8)*258 + px;   // tap row base
    s16x2 lq[3][3];
    uint2 ta[3][3];
    #pragma unroll
    for (int rr = 0; rr < 2; ++rr){
        #pragma unroll
        for (int c = 0; c < 3; ++c){
            lq[rr][c] = __builtin_bit_cast(s16x2, Lq[(size_t)rr*258 + c]);
            ta[rr][c] = h2t[rr][px + c];
        }
    }
    #pragma unroll
    for (int r = 0; r < 8; ++r){
        #pragma unroll
        for (int c = 0; c < 3; ++c){
            lq[2][c] = __builtin_bit_cast(s16x2, Lq[(size_t)(r+2)*258 + c]);
            ta[2][c] = h2t[r+2][px + c];
        }
        float sl0 = 0.f, sl1 = 0.f, sh0 = 0.f, sh1 = 0.f;
        #pragma unroll
        for (int dy = 0; dy < 3; ++dy){
            #pragma unroll
            for (int dx = 0; dx < 3; ++dx){
                int q = dy*3 + dx;
                if (q & 1){ sl1 = DOT2B(lq[dy][dx], WPl[q], sl1); sh1 = DOT2B(lq[dy][dx], WPh[q], sh1); }
                else      { sl0 = DOT2B(lq[dy][dx], WPl[q], sl0); sh0 = DOT2B(lq[dy][dx], WPh[q], sh0); }
            }
        }
        if (lbr){
            #pragma unroll
            for (int dy = 0; dy < 3; ++dy){
                #pragma unroll
                for (int dx = 0; dx < 3; ++dx){
                    int q = dy*3 + dx;
                    uint2 tv = ta[dy][dx];
                    sl0 = DOT2B(__builtin_bit_cast(s16x2, tv.x), WDl[2*q],   sl0);
                    sl1 = DOT2B(__builtin_bit_cast(s16x2, tv.y), WDl[2*q+1], sl1);
                }
            }
        }
        if (hbr){
            #pragma unroll
            for (int dy = 0; dy < 3; ++dy){
                #pragma unroll
                for (int dx = 0; dx < 3; ++dx){
                    int q = dy*3 + dx;
                    uint2 tv = ta[dy][dx];
                    sh0 = DOT2B(__builtin_bit_cast(s16x2, tv.x), WDh[2*q],   sh0);
                    sh1 = DOT2B(__builtin_bit_cast(s16x2, tv.y), WDh[2*q+1], sh1);
                }
            }
        }
        vb[(size_t)r*256] = pk2c(fmaxf(sl0+sl1, 0.f), fmaxf(sh0+sh1, 0.f));
        if (g == 126) vb[(size_t)r*256 + ps] = 0u;   // zero pad plane 127
        #pragma unroll
        for (int c = 0; c < 3; ++c){
            ta[0][c] = ta[1][c]; ta[1][c] = ta[2][c];
            lq[0][c] = lq[1][c]; lq[1][c] = lq[2][c];
        }
    }
}

// ---------------- K4: out = v @ BtP^T + x via MFMA, fused residual ----------------
__global__ __launch_bounds__(256) void k_proj(const unsigned int* __restrict__ v,
        const unsigned short* __restrict__ BtP, const float* __restrict__ x,
        float* __restrict__ out, int b0, int a, int orows){
    __shared__ float EoS[256*49];            // 50176 B; Bt overlays first 26112 B
    unsigned short* Bt = (unsigned short*)EoS;   // [48 n][136 u16]
    int t = threadIdx.x;
    for (int i = t; i < 48*256; i += 256){
        int n = i >> 8, k = i & 255;
        Bt[n*136 + k] = BtP[i];
    }
    int bi = blockIdx.x / orows;
    int lr = blockIdx.x - bi*orows;
    int b = b0 + bi;
    size_t ps = (size_t)orows*256;
    const unsigned int* vb = v + (size_t)bi*128*ps + (size_t)lr*256;
    int lane = t & 63, w = t >> 6;
    int pxl = w*64;
    __syncthreads();
    f32x4 acc[4][3];
    #pragma unroll
    for (int m = 0; m < 4; ++m)
        #pragma unroll
        for (int nt = 0; nt < 3; ++nt) acc[m][nt] = (f32x4){0.f,0.f,0.f,0.f};
    #pragma unroll
    for (int ch = 0; ch < 4; ++ch){
        bf16x8 bfr[3][2];
        #pragma unroll
        for (int nt = 0; nt < 3; ++nt)
            #pragma unroll
            for (int kk = 0; kk < 2; ++kk)
                bfr[nt][kk] = *reinterpret_cast<const bf16x8*>(
                    &Bt[(nt*16 + (lane&15))*136 + ch*64 + kk*32 + (lane>>4)*8]);
        #pragma unroll
        for (int m = 0; m < 4; ++m){
            int px = pxl + m*16 + (lane & 15);
            #pragma unroll
            for (int kk = 0; kk < 2; ++kk){
                int pl0 = ch*32 + kk*16 + (lane>>4)*4;
                unsigned int p0 = vb[(size_t)(pl0+0)*ps + px];
                unsigned int p1 = vb[(size_t)(pl0+1)*ps + px];
                unsigned int p2 = vb[(size_t)(pl0+2)*ps + px];
                unsigned int p3 = vb[(size_t)(pl0+3)*ps + px];
                bf16x8 af;
                af[0]=(short)(p0&0xffff); af[1]=(short)(p0>>16);
                af[2]=(short)(p1&0xffff); af[3]=(short)(p1>>16);
                af[4]=(short)(p2&0xffff); af[5]=(short)(p2>>16);
                af[6]=(short)(p3&0xffff); af[7]=(short)(p3>>16);
                #pragma unroll
                for (int nt = 0; nt < 3; ++nt)
                    acc[m][nt] = __builtin_amdgcn_mfma_f32_16x16x32_bf16(af, bfr[nt][kk], acc[m][nt], 0, 0, 0);
            }
        }
    }
    __syncthreads();   // Bt dead -> epilogue buffer
    #pragma unroll
    for (int m = 0; m < 4; ++m){
        #pragma unroll
        for (int nt = 0; nt < 3; ++nt){
            #pragma unroll
            for (int rg = 0; rg < 4; ++rg){
                int epx = pxl + m*16 + (lane>>4)*4 + rg;
                int eo  = nt*16 + (lane&15);
                EoS[epx*49 + eo] = acc[m][nt][rg];
            }
        }
    }
    __syncthreads();
    int grow = a + lr;
    const float* xb = x + (size_t)b*48*HW + (size_t)grow*256 + t;
    float* ob = out + (size_t)b*48*HW + (size_t)grow*256 + t;
    #pragma unroll
    for (int o = 0; o < 48; ++o)
        ob[(size_t)o*HW] = EoS[t*49 + o] + xb[(size_t)o*HW];
}

extern "C" void kernel_launch(void* const* d_in, const int* in_sizes, int n_in,
                              void* d_out, int out_size, void* d_ws, size_t ws_size,
                              hipStream_t stream){
    const float* x    = (const float*)d_in[0];
    const float* winP = (const float*)d_in[1];
    const float* winD = (const float*)d_in[2];
    const float* wlp1 = (const float*)d_in[3];
    const float* whp1 = (const float*)d_in[4];
    const float* wlp2 = (const float*)d_in[5];
    const float* whp2 = (const float*)d_in[6];
    const float* wld  = (const float*)d_in[7];
    const float* whd  = (const float*)d_in[8];
    const float* wout = (const float*)d_in[9];
    float* out = (float*)d_out;

    char* ws = (char*)d_ws;
    size_t off = 0;
    auto alloc = [&](size_t bytes)->char*{
        char* pp = ws + off; off += (bytes + 255) & ~(size_t)255; return pp;
    };
    auto A = [](size_t bytes)->size_t{ return (bytes + 255) & ~(size_t)255; };

    float* ahp1s = (float*)alloc(508*4);
    float* cpG = (float*)alloc(508*4);
    float* cnG = (float*)alloc(508*4);
    unsigned int* WPNL  = (unsigned int*)alloc(127*9*4);
    unsigned int* WPNH  = (unsigned int*)alloc(127*9*4);
    unsigned int* WLDpk = (unsigned int*)alloc(127*18*4);
    unsigned int* WHDpk = (unsigned int*)alloc(127*18*4);
    float* wDp  = (float*)alloc(512*9*4);
    unsigned short* WPb = (unsigned short*)alloc(256*64*2);
    unsigned short* BtP = (unsigned short*)alloc(48*256*2);

    // ladder: Hb must be a multiple of 8 (k_mov tiles)
    const int cfgs[6][2] = {{256,2},{128,2},{64,2},{64,1},{32,1},{16,1}};
    int Hb = 16, nbat = 1;
    for (int ci = 0; ci < 6; ++ci){
        int hb = cfgs[ci][0], nb = cfgs[ci][1];
        int uRr = hb+6 < 256 ? hb+6 : 256;
        int tRr = hb+4 < 256 ? hb+4 : 256;
        size_t need = off;
        need += A((size_t)nb*32*(uRr+2)*258*16);   // u (padded oct layout; v aliases it)
        need += A((size_t)nb*508*tRr*256*2);       // d1s (508 u16 planes)
        need += A((size_t)nb*NCH*tRr*256*4);       // Sp
        need += A((size_t)nb*(hb+2)*258*4);        // Lm (padded)
        need += A((size_t)nb*(hb+2)*258*4);        // Lpk (padded)
        if (need <= ws_size){ Hb = hb; nbat = nb; break; }
    }
    int uR = Hb+6 < 256 ? Hb+6 : 256;
    int tR = Hb+4 < 256 ? Hb+4 : 256;
    int uRp = uR + 2;
    int lRp = Hb + 2;
    uint4* u   = (uint4*)alloc((size_t)nbat*32*uRp*258*16);
    unsigned short* d1s = (unsigned short*)alloc((size_t)nbat*508*tR*256*2);
    float* Sp = (float*)alloc((size_t)nbat*NCH*tR*256*4);
    float* Lm = (float*)alloc((size_t)nbat*lRp*258*4);
    unsigned int* Lpk = (unsigned int*)alloc((size_t)nbat*lRp*258*4);
    // v aliases u: u is dead after k_dw; per-band order pconv->dw->mov->proj keeps it safe.
    unsigned int* v = (unsigned int*)u;

    k_coef1<<<1, 512, 0, stream>>>(wlp1, whp1, wlp2, ahp1s, cpG, cnG);
    k_coef2<<<64, 256, 0, stream>>>(wld, whd, winP, winD, wout, cpG, cnG,
                                    WPNL, WPNH, WLDpk, WHDpk, wDp, WPb, BtP);

    for (int b0 = 0; b0 < 2; b0 += nbat){
        for (int a = 0; a < 256; a += Hb){
            int ur0 = a-3 > 0 ? a-3 : 0;  int ur1 = a+Hb+3 < 256 ? a+Hb+3 : 256;
            int tr0 = a-2 > 0 ? a-2 : 0;  int tr1 = a+Hb+2 < 256 ? a+Hb+2 : 256;
            int lr0 = a-1 > 0 ? a-1 : 0;  int lr1 = a+Hb+1 < 256 ? a+Hb+1 : 256;
            int urows = ur1-ur0, trows = tr1-tr0, lrows = lr1-lr0;
            int orows = (a+Hb < 256 ? a+Hb : 256) - a;
            k_padU<<<nbat*32 + nbat, 256, 0, stream>>>(u, Lm, Lpk, uRp, lRp, nbat,
                                                       a == 0, a + Hb >= 256);
            k_pconv<<<nbat*urows*4, 256, 0, stream>>>(x, WPb, u, b0, ur0, urows, uRp);
            k_dw  <<<nbat*trows*NCH, 256, 0, stream>>>(u, wDp, whp1, d1s, Sp, tr0, trows, ur0, uRp, tR, nbat);
            k_box <<<nbat*lrows, 256, 0, stream>>>(Sp, Lm, Lpk, lr0, lrows, tr0, tR, a, lRp, nbat);
            k_mov <<<nbat*(orows>>3)*127, 256, 0, stream>>>(d1s, Lm, Lpk, whp2, ahp1s,
                                                            WPNL, WPNH, WLDpk, WHDpk, v,
                                                            a, orows, tr0, tR, lRp);
            k_proj<<<nbat*orows, 256, 0, stream>>>(v, BtP, x, out, b0, a, orows);
        }
    }
}